// Round 5
// baseline (133761.536 us; speedup 1.0000x reference)
//
#include <hip/hip_runtime.h>
#include <math.h>

#define T_DIM 512
#define B_DIM 64
#define I_DIM 1024
#define H_DIM 1024

// d_out layout (flat f32): ys [T][B][2H], hT_f [B][H], cT_f, hT_b, cT_b
#define OUT_HTF (T_DIM * B_DIM * 2 * H_DIM)
#define OUT_CTF (OUT_HTF + B_DIM * H_DIM)
#define OUT_HTB (OUT_CTF + B_DIM * H_DIM)
#define OUT_CTB (OUT_HTB + B_DIM * H_DIM)

__device__ __forceinline__ float sigmoidf_(float v) {
    return 1.0f / (1.0f + expf(-v));
}

// Persistent bidirectional LSTM, W via scalar loads (SGPR operands).
// Grid: 256 blocks x 512 threads (8 waves), exactly 1 block/CU (81.9 KB LDS).
// Block bid: dir = bid>>7, u0 = (bid&127)*8 -> owns 32 gate-rows {i,f,g,o}x8u.
// Wave wid (uniform via readfirstlane): gate g = wid>>1, unit-quad = wid&1.
// Thread: lane = batch row m (0..63), computes 4 gate-rows (its quad's units).
// W addresses are wave-uniform -> s_load into SGPRs -> v_fma with SGPR src:
// W traffic rides the scalar pipe, not LDS/VMEM. h/x staged in LDS, swizzled.
// Per step: gates = accx (x-part computed LAST step) + h @ W_hh^T; meanwhile
// accumulate accxn = x_next @ W_ih^T (latency-tolerant). c-state in 1 reg.
__global__ __launch_bounds__(512, 2) void lstm_persist2(
    const float* __restrict__ x,
    const float* __restrict__ h0f, const float* __restrict__ c0f,
    const float* __restrict__ h0b, const float* __restrict__ c0b,
    const float* __restrict__ wihf, const float* __restrict__ whhf,
    const float* __restrict__ bihf, const float* __restrict__ bhhf,
    const float* __restrict__ wihb, const float* __restrict__ whhb,
    const float* __restrict__ bihb, const float* __restrict__ bhhb,
    float* __restrict__ out, int* __restrict__ bar)
{
    __shared__ float smem[2 * 8192 + 4096];  // 81.9 KB -> 1 block/CU
    float* stage = smem;                     // 2 x [64 m][128 k], swizzled
    float* gsm   = smem + 16384;             // gate exchange [32 rows][72]

    const int tid  = threadIdx.x;
    const int bid  = blockIdx.x;
    const int dir  = bid >> 7;
    const int u0   = (bid & 127) * 8;
    const int lane = tid & 63;               // batch row m
    const int wid  = __builtin_amdgcn_readfirstlane(tid >> 6); // 0..7 uniform
    const int g    = wid >> 1;               // gate 0..3
    const int quad = wid & 1;                // unit quad 0..1

    const float* wih = dir ? wihb : wihf;
    const float* whh = dir ? whhb : whhf;
    const float* bih = dir ? bihb : bihf;
    const float* bhh = dir ? bhhb : bhhf;

    const int rbase = g * H_DIM + u0 + quad * 4;   // uniform W row base
    float bias[4];
#pragma unroll
    for (int ci = 0; ci < 4; ++ci) bias[ci] = bih[rbase + ci] + bhh[rbase + ci];

    // persistent c-state: one cell (cm, u0+uo) per thread
    const int uo = tid & 7;
    const int cm = tid >> 3;                 // 0..63
    const float* cinit = dir ? c0b : c0f;
    float creg = cinit[(size_t)cm * H_DIM + u0 + uo];

    float4 ld[4];
    auto issue_stage = [&](const float* src, int stride, int kb) {
#pragma unroll
        for (int p = 0; p < 4; ++p) {
            const int e = p * 512 + tid;     // float4 slot 0..2047
            const int m = e >> 5, q = e & 31;
            ld[p] = *reinterpret_cast<const float4*>(
                src + (size_t)m * stride + kb + q * 4);
        }
    };
    auto write_stage = [&](int buf) {
        float* dst = stage + buf * 8192;
#pragma unroll
        for (int p = 0; p < 4; ++p) {
            const int e = p * 512 + tid;
            const int m = e >> 5, q = e & 31;
            *reinterpret_cast<float4*>(&dst[m * 128 + ((q ^ (m & 31)) * 4)]) = ld[p];
        }
    };
    auto compute = [&](const float* wsrc, int kb, int buf, float* acc) {
        const float* wb = wsrc + (size_t)rbase * 1024 + kb;  // uniform -> s_load
        const float* sb = stage + buf * 8192 + lane * 128;
        const int msw = lane & 31;
#pragma unroll 8
        for (int q = 0; q < 32; ++q) {
            const float4 a = *reinterpret_cast<const float4*>(&sb[(q ^ msw) * 4]);
#pragma unroll
            for (int ci = 0; ci < 4; ++ci) {
                const float* wr = wb + ci * 1024 + q * 4;
                acc[ci] = fmaf(a.x, wr[0], fmaf(a.y, wr[1],
                          fmaf(a.z, wr[2], fmaf(a.w, wr[3], acc[ci]))));
            }
        }
    };

    // ---- prologue: accx = x_{t0} @ W_ih^T + bias ----
    float accx[4];
#pragma unroll
    for (int ci = 0; ci < 4; ++ci) accx[ci] = bias[ci];
    {
        const int t0 = dir ? (T_DIM - 1) : 0;
        const float* xs = x + (size_t)t0 * B_DIM * I_DIM;
        issue_stage(xs, I_DIM, 0);
        write_stage(0);
        __syncthreads();
        for (int c = 0; c < 8; ++c) {
            if (c < 7) issue_stage(xs, I_DIM, (c + 1) * 128);
            compute(wih, c * 128, c & 1, accx);
            __syncthreads();
            if (c < 7) { write_stage((c + 1) & 1); __syncthreads(); }
        }
    }

    // ---- main recurrence ----
    for (int s = 0; s < T_DIM; ++s) {
        const int t = dir ? (T_DIM - 1 - s) : s;
        const float* hprev;
        int hst;
        if (s == 0) {
            hprev = dir ? h0b : h0f;
            hst = H_DIM;
        } else {
            const int tp = dir ? (t + 1) : (t - 1);
            hprev = out + (size_t)tp * B_DIM * 2 * H_DIM + dir * H_DIM;
            hst = 2 * H_DIM;
        }
        const bool hasx = (s < T_DIM - 1);
        const int tn = dir ? (t - 1) : (t + 1);
        const float* xn = x + (size_t)(hasx ? tn : t) * B_DIM * I_DIM;
        const int nch = hasx ? 16 : 8;

        float acch[4] = {0.f, 0.f, 0.f, 0.f};
        float accxn[4];
#pragma unroll
        for (int ci = 0; ci < 4; ++ci) accxn[ci] = bias[ci];

        // chunks 0..7 = h (W_hh); 8..15 = x_next (W_ih)
        issue_stage(hprev, hst, 0);
        write_stage(0);
        __syncthreads();
        for (int c = 0; c < nch; ++c) {
            if (c + 1 < nch) {
                if (c + 1 < 8) issue_stage(hprev, hst, (c + 1) * 128);
                else           issue_stage(xn, I_DIM, (c + 1 - 8) * 128);
            }
            if (c < 8) compute(whh, c * 128, c & 1, acch);
            else       compute(wih, (c - 8) * 128, c & 1, accxn);
            __syncthreads();
            if (c + 1 < nch) { write_stage((c + 1) & 1); __syncthreads(); }
        }

        // ---- gate exchange: gsm[gate*8 + unit][m], stride 72 ----
#pragma unroll
        for (int ci = 0; ci < 4; ++ci)
            gsm[(g * 8 + quad * 4 + ci) * 72 + lane] = accx[ci] + acch[ci];
        __syncthreads();

        // ---- cell update: 1 cell per thread ----
        const float ig = gsm[(0  + uo) * 72 + cm];
        const float fg = gsm[(8  + uo) * 72 + cm];
        const float gg = gsm[(16 + uo) * 72 + cm];
        const float og = gsm[(24 + uo) * 72 + cm];
        const float cn = sigmoidf_(fg) * creg + sigmoidf_(ig) * tanhf(gg);
        const float hv = sigmoidf_(og) * tanhf(cn);
        creg = cn;
        out[(size_t)t * B_DIM * 2 * H_DIM + (size_t)cm * 2 * H_DIM
            + dir * H_DIM + u0 + uo] = hv;
        if (s == T_DIM - 1) {
            float* hslot = out + (dir ? OUT_HTB : OUT_HTF);
            float* cslot = out + (dir ? OUT_CTB : OUT_CTF);
            hslot[(size_t)cm * H_DIM + u0 + uo] = hv;
            cslot[(size_t)cm * H_DIM + u0 + uo] = creg;
        }

        // ---- grid barrier (2-level, agent-scope, generation s+1) ----
        if (s < T_DIM - 1) {
            __threadfence();               // make h-writes visible device-wide
            __syncthreads();
            if (tid == 0) {
                const int grp = bid >> 5;  // 8 groups of 32 blocks
                __hip_atomic_fetch_add(&bar[grp], 1, __ATOMIC_RELEASE,
                                       __HIP_MEMORY_SCOPE_AGENT);
                if ((bid & 31) == 0) {
                    while (__hip_atomic_load(&bar[grp], __ATOMIC_ACQUIRE,
                                             __HIP_MEMORY_SCOPE_AGENT)
                           < 32 * (s + 1))
                        __builtin_amdgcn_s_sleep(2);
                    __hip_atomic_fetch_add(&bar[8], 1, __ATOMIC_RELEASE,
                                           __HIP_MEMORY_SCOPE_AGENT);
                }
                while (__hip_atomic_load(&bar[8], __ATOMIC_ACQUIRE,
                                         __HIP_MEMORY_SCOPE_AGENT)
                       < 8 * (s + 1))
                    __builtin_amdgcn_s_sleep(2);
            }
            __syncthreads();
            __threadfence();               // acquire side

#pragma unroll
            for (int ci = 0; ci < 4; ++ci) accx[ci] = accxn[ci];
        }
    }
}

extern "C" void kernel_launch(void* const* d_in, const int* in_sizes, int n_in,
                              void* d_out, int out_size, void* d_ws, size_t ws_size,
                              hipStream_t stream)
{
    const float* x    = (const float*)d_in[0];
    const float* h0f  = (const float*)d_in[1];
    const float* c0f  = (const float*)d_in[2];
    const float* h0b  = (const float*)d_in[3];
    const float* c0b  = (const float*)d_in[4];
    const float* wihf = (const float*)d_in[5];
    const float* whhf = (const float*)d_in[6];
    const float* bihf = (const float*)d_in[7];
    const float* bhhf = (const float*)d_in[8];
    const float* wihb = (const float*)d_in[9];
    const float* whhb = (const float*)d_in[10];
    const float* bihb = (const float*)d_in[11];
    const float* bhhb = (const float*)d_in[12];
    float* out = (float*)d_out;

    // barrier counters (9 ints) — must be zero at each call
    hipMemsetAsync(d_ws, 0, 64, stream);
    lstm_persist2<<<dim3(256), dim3(512), 0, stream>>>(
        x, h0f, c0f, h0b, c0b,
        wihf, whhf, bihf, bhhf,
        wihb, whhb, bihb, bhhb,
        out, (int*)d_ws);
}

// Round 6
// 90149.701 us; speedup vs baseline: 1.4838x; 1.4838x over previous
//
#include <hip/hip_runtime.h>
#include <math.h>

#define T_DIM 512
#define B_DIM 64
#define I_DIM 1024
#define H_DIM 1024

// d_out layout (flat f32): ys [T][B][2H], hT_f [B][H], cT_f, hT_b, cT_b
#define OUT_HTF (T_DIM * B_DIM * 2 * H_DIM)
#define OUT_CTF (OUT_HTF + B_DIM * H_DIM)
#define OUT_HTB (OUT_CTF + B_DIM * H_DIM)
#define OUT_CTB (OUT_HTB + B_DIM * H_DIM)

__device__ __forceinline__ float sigmoidf_(float v) {
    return 1.0f / (1.0f + expf(-v));
}

// ---------------------------------------------------------------------------
// Persistent producer/consumer bidirectional LSTM.
// Grid: 256 blocks x 512 threads, 1 block/CU (83 KB LDS forces it).
//   bid <  128 : h-role  — gates += h_prev @ W_hh^T (+gx), cell update
//   bid >= 128 : x-role  — gx[t] = x_t @ W_ih^T + bias, 1 step ahead (ring=2)
// Role id: dir = rid>>6, jblk = rid&63 -> block owns 64 gate-cols jj where
//   jj -> gate = jj>>4, unit = jblk*16 + (jj&15)  (all 4 gates of 16 units).
// GEMM: 64m x 64j x 1024k. 8 waves k-split (128k each). Lane (mg=l&7, jg=l>>3)
// owns an 8m x 8j register tile (acc[8][8]); A and W both read straight from
// global memory as float4 (L2/L3-resident; coalesced 8-line requests, 8x
// wave-dup handled by the coalescer). No LDS in the inner loop.
// 8 wave-partials tree-reduced via LDS; wave 0 finalizes.
// c-state: 2 registers/thread, persistent. Grid barrier per round.
// ---------------------------------------------------------------------------
__global__ __launch_bounds__(512, 2) void lstm_pc(
    const float* __restrict__ x,
    const float* __restrict__ h0f, const float* __restrict__ c0f,
    const float* __restrict__ h0b, const float* __restrict__ c0b,
    const float* __restrict__ wihf, const float* __restrict__ whhf,
    const float* __restrict__ bihf, const float* __restrict__ bhhf,
    const float* __restrict__ wihb, const float* __restrict__ whhb,
    const float* __restrict__ bihb, const float* __restrict__ bhhb,
    float* __restrict__ out, float* __restrict__ gx, int* __restrict__ bar)
{
    __shared__ float Lred[16384];          // 64 KB reduce buffer (4 regions)
    __shared__ float Lg[64 * 68 + 16];     // 17 KB gate buffer (padded rows)

    const int tid  = threadIdx.x;
    const int bid  = blockIdx.x;
    const bool hrole = (bid < 128);
    const int rid  = hrole ? bid : bid - 128;
    const int dir  = rid >> 6;
    const int jblk = rid & 63;
    const int u0   = jblk * 16;
    const int wid  = tid >> 6;             // wave 0..7 -> k-slice
    const int lane = tid & 63;
    const int mg   = lane & 7;             // m-group: rows mg*8..+7
    const int jg   = lane >> 3;            // j-group: cols jg*8..+7
    const int gate = jg >> 1;

    // this lane's 8 contiguous W rows / gate-cols
    const int wrow0 = gate * H_DIM + u0 + (jg & 1) * 8;
    const float* W  = hrole ? (dir ? whhb : whhf) : (dir ? wihb : wihf);
    const float* wk[8];
#pragma unroll
    for (int c = 0; c < 8; ++c)
        wk[c] = W + (size_t)(wrow0 + c) * 1024 + wid * 128;

    // x-role: bias per gate-col, cached in regs (b_ih + b_hh)
    float bias8[8];
    if (!hrole) {
        const float* bi = dir ? bihb : bihf;
        const float* bh = dir ? bhhb : bhhf;
#pragma unroll
        for (int c = 0; c < 8; ++c)
            bias8[c] = bi[wrow0 + c] + bh[wrow0 + c];
    }

    // h-role: persistent c-state, 2 cells (m, u0+up), (m, u0+up+1)
    const int cm = tid >> 3;               // 0..63
    const int up = (tid & 7) * 2;
    float cr0 = 0.f, cr1 = 0.f;
    if (hrole) {
        const float* ci = dir ? c0b : c0f;
        cr0 = ci[(size_t)cm * H_DIM + u0 + up];
        cr1 = ci[(size_t)cm * H_DIM + u0 + up + 1];
    }

    float acc[8][8];

    auto gemm = [&](const float* ap, int sA) {
        const float* ar[8];
#pragma unroll
        for (int i = 0; i < 8; ++i)
            ar[i] = ap + (size_t)(mg * 8 + i) * sA + wid * 128;
#pragma unroll 2
        for (int kq = 0; kq < 32; ++kq) {
            float4 a[8], w[8];
#pragma unroll
            for (int i = 0; i < 8; ++i)
                a[i] = *reinterpret_cast<const float4*>(ar[i] + kq * 4);
#pragma unroll
            for (int c = 0; c < 8; ++c)
                w[c] = *reinterpret_cast<const float4*>(wk[c] + kq * 4);
#pragma unroll
            for (int i = 0; i < 8; ++i)
#pragma unroll
                for (int c = 0; c < 8; ++c)
                    acc[i][c] = fmaf(a[i].x, w[c].x, fmaf(a[i].y, w[c].y,
                                fmaf(a[i].z, w[c].z, fmaf(a[i].w, w[c].w,
                                     acc[i][c]))));
        }
    };

    auto wracc = [&](float* b) {
#pragma unroll
        for (int i = 0; i < 8; ++i) {
            float4 v0 = make_float4(acc[i][0], acc[i][1], acc[i][2], acc[i][3]);
            float4 v1 = make_float4(acc[i][4], acc[i][5], acc[i][6], acc[i][7]);
            float* p = b + (mg * 8 + i) * 64 + jg * 8;
            *reinterpret_cast<float4*>(p)     = v0;
            *reinterpret_cast<float4*>(p + 4) = v1;
        }
    };
    auto rdacc = [&](const float* b) {
#pragma unroll
        for (int i = 0; i < 8; ++i) {
            const float* p = b + (mg * 8 + i) * 64 + jg * 8;
            const float4 v0 = *reinterpret_cast<const float4*>(p);
            const float4 v1 = *reinterpret_cast<const float4*>(p + 4);
            acc[i][0] += v0.x; acc[i][1] += v0.y;
            acc[i][2] += v0.z; acc[i][3] += v0.w;
            acc[i][4] += v1.x; acc[i][5] += v1.y;
            acc[i][6] += v1.z; acc[i][7] += v1.w;
        }
    };

    // rounds: r=0 x-prologue; r=1..512: h computes s=r-1 while x computes t=r
    for (int r = 0; r < T_DIM + 1; ++r) {
        const bool active = hrole ? (r >= 1) : (r < T_DIM);

        if (active) {
            if (hrole) {
                const int s = r - 1;
                const int t = dir ? (T_DIM - 1 - s) : s;
                // acc init: wave 0 loads gx chunk, others zero
                if (wid == 0) {
                    const float* gc = gx
                        + (((size_t)((s & 1) * 2 + dir)) * 64 + jblk) * 4096
                        + (mg * 8) * 64 + jg * 8;
#pragma unroll
                    for (int i = 0; i < 8; ++i) {
                        const float4 v0 =
                            *reinterpret_cast<const float4*>(gc + i * 64);
                        const float4 v1 =
                            *reinterpret_cast<const float4*>(gc + i * 64 + 4);
                        acc[i][0] = v0.x; acc[i][1] = v0.y;
                        acc[i][2] = v0.z; acc[i][3] = v0.w;
                        acc[i][4] = v1.x; acc[i][5] = v1.y;
                        acc[i][6] = v1.z; acc[i][7] = v1.w;
                    }
                } else {
#pragma unroll
                    for (int i = 0; i < 8; ++i)
#pragma unroll
                        for (int c = 0; c < 8; ++c) acc[i][c] = 0.f;
                }
                // h-GEMM
                if (s == 0) {
                    gemm(dir ? h0b : h0f, H_DIM);
                } else {
                    const int tp = dir ? (t + 1) : (t - 1);
                    gemm(out + (size_t)tp * B_DIM * 2 * H_DIM + dir * H_DIM,
                         2 * H_DIM);
                }
            } else {
                const int tx = r;
                const int t = dir ? (T_DIM - 1 - tx) : tx;
                if (wid == 0) {
#pragma unroll
                    for (int i = 0; i < 8; ++i)
#pragma unroll
                        for (int c = 0; c < 8; ++c) acc[i][c] = bias8[c];
                } else {
#pragma unroll
                    for (int i = 0; i < 8; ++i)
#pragma unroll
                        for (int c = 0; c < 8; ++c) acc[i][c] = 0.f;
                }
                gemm(x + (size_t)t * B_DIM * I_DIM, I_DIM);
            }

            // ---- tree-reduce 8 wave-partials -> wave 0 ----
            if (wid & 1) wracc(Lred + (wid >> 1) * 4096);
            __syncthreads();
            if (!(wid & 1)) rdacc(Lred + (wid >> 1) * 4096);
            __syncthreads();
            if (wid == 2) wracc(Lred);
            if (wid == 6) wracc(Lred + 4096);
            __syncthreads();
            if (wid == 0) rdacc(Lred);
            if (wid == 4) rdacc(Lred + 4096);
            __syncthreads();
            if (wid == 4) wracc(Lred);
            __syncthreads();
            if (wid == 0) rdacc(Lred);

            if (hrole) {
                const int s = r - 1;
                const int t = dir ? (T_DIM - 1 - s) : s;
                // wave 0 -> Lg[m][jj], stride 68
                if (wid == 0) {
#pragma unroll
                    for (int i = 0; i < 8; ++i) {
                        float* p = Lg + (mg * 8 + i) * 68 + jg * 8;
                        *reinterpret_cast<float4*>(p) = make_float4(
                            acc[i][0], acc[i][1], acc[i][2], acc[i][3]);
                        *reinterpret_cast<float4*>(p + 4) = make_float4(
                            acc[i][4], acc[i][5], acc[i][6], acc[i][7]);
                    }
                }
                __syncthreads();
                // cell update: 2 cells/thread
                const float ig0 = Lg[cm * 68 + 0  + up], ig1 = Lg[cm * 68 + 0  + up + 1];
                const float fg0 = Lg[cm * 68 + 16 + up], fg1 = Lg[cm * 68 + 16 + up + 1];
                const float gg0 = Lg[cm * 68 + 32 + up], gg1 = Lg[cm * 68 + 32 + up + 1];
                const float og0 = Lg[cm * 68 + 48 + up], og1 = Lg[cm * 68 + 48 + up + 1];
                cr0 = sigmoidf_(fg0) * cr0 + sigmoidf_(ig0) * tanhf(gg0);
                cr1 = sigmoidf_(fg1) * cr1 + sigmoidf_(ig1) * tanhf(gg1);
                const float hv0 = sigmoidf_(og0) * tanhf(cr0);
                const float hv1 = sigmoidf_(og1) * tanhf(cr1);
                float* op = out + (size_t)t * B_DIM * 2 * H_DIM
                            + (size_t)cm * 2 * H_DIM + dir * H_DIM + u0 + up;
                *reinterpret_cast<float2*>(op) = make_float2(hv0, hv1);
                if (s == T_DIM - 1) {
                    float* hs = out + (dir ? OUT_HTB : OUT_HTF);
                    float* cs = out + (dir ? OUT_CTB : OUT_CTF);
                    *reinterpret_cast<float2*>(
                        hs + (size_t)cm * H_DIM + u0 + up) = make_float2(hv0, hv1);
                    *reinterpret_cast<float2*>(
                        cs + (size_t)cm * H_DIM + u0 + up) = make_float2(cr0, cr1);
                }
                __syncthreads();           // Lg reuse safety next round
            } else {
                const int tx = r;
                // wave 0 -> gx ring slot tx&1
                if (wid == 0) {
                    float* gw = gx
                        + (((size_t)((tx & 1) * 2 + dir)) * 64 + jblk) * 4096
                        + (mg * 8) * 64 + jg * 8;
#pragma unroll
                    for (int i = 0; i < 8; ++i) {
                        *reinterpret_cast<float4*>(gw + i * 64) = make_float4(
                            acc[i][0], acc[i][1], acc[i][2], acc[i][3]);
                        *reinterpret_cast<float4*>(gw + i * 64 + 4) = make_float4(
                            acc[i][4], acc[i][5], acc[i][6], acc[i][7]);
                    }
                }
            }
        }

        // ---- grid barrier, generation r+1 (skip after final round) ----
        if (r < T_DIM) {
            __threadfence();
            __syncthreads();
            if (tid == 0) {
                const int grp = bid >> 5;
                __hip_atomic_fetch_add(&bar[grp], 1, __ATOMIC_RELEASE,
                                       __HIP_MEMORY_SCOPE_AGENT);
                if ((bid & 31) == 0) {
                    while (__hip_atomic_load(&bar[grp], __ATOMIC_ACQUIRE,
                                             __HIP_MEMORY_SCOPE_AGENT)
                           < 32 * (r + 1))
                        __builtin_amdgcn_s_sleep(2);
                    __hip_atomic_fetch_add(&bar[8], 1, __ATOMIC_RELEASE,
                                           __HIP_MEMORY_SCOPE_AGENT);
                }
                while (__hip_atomic_load(&bar[8], __ATOMIC_ACQUIRE,
                                         __HIP_MEMORY_SCOPE_AGENT)
                       < 8 * (r + 1))
                    __builtin_amdgcn_s_sleep(2);
            }
            __syncthreads();
            __threadfence();
        }
    }
}

// ---------------------------------------------------------------------------
// Fallback (ws too small): round-2 fused per-step kernel (proven correct).
// ---------------------------------------------------------------------------
__global__ __launch_bounds__(256, 1) void lstm_step_fused(
    const float* __restrict__ x,
    const float* __restrict__ h0f, const float* __restrict__ c0f,
    const float* __restrict__ h0b, const float* __restrict__ c0b,
    const float* __restrict__ wihf, const float* __restrict__ whhf,
    const float* __restrict__ bihf, const float* __restrict__ bhhf,
    const float* __restrict__ wihb, const float* __restrict__ whhb,
    const float* __restrict__ bihb, const float* __restrict__ bhhb,
    float* __restrict__ out, int step)
{
    __shared__ float smem[2 * 64 * 128];
    const int tid = threadIdx.x, bid = blockIdx.x;
    const int dir = bid >> 7, u0 = (bid & 127) * 8;
    const int t = dir ? (T_DIM - 1 - step) : step;
    const int lane = tid & 63, g = tid >> 6;
    const float* w_ih = dir ? wihb : wihf;
    const float* w_hh = dir ? whhb : whhf;
    const float* bih = dir ? bihb : bihf;
    const float* bhh = dir ? bhhb : bhhf;
    const float* xt = x + (size_t)t * B_DIM * I_DIM;
    const float* hprev; int hst;
    if (step == 0) { hprev = dir ? h0b : h0f; hst = H_DIM; }
    else {
        const int tp = dir ? (t + 1) : (t - 1);
        hprev = out + (size_t)tp * B_DIM * 2 * H_DIM + dir * H_DIM;
        hst = 2 * H_DIM;
    }
    const int row0 = g * H_DIM + u0;
    float acc[8];
#pragma unroll
    for (int ci = 0; ci < 8; ++ci) acc[ci] = bih[row0 + ci] + bhh[row0 + ci];
    float4 ld[8];
    auto issue = [&](int kc) {
        const bool isX = (kc < 8);
        const float* src = isX ? xt : hprev;
        const int stride = isX ? I_DIM : hst;
        const int kb = (kc & 7) * 128;
#pragma unroll
        for (int p = 0; p < 8; ++p) {
            const int e = p * 256 + tid, m = e >> 5, q = e & 31;
            ld[p] = *reinterpret_cast<const float4*>(
                src + (size_t)m * stride + kb + q * 4);
        }
    };
    auto wstage = [&](int buf) {
        float* dst = smem + buf * 8192;
#pragma unroll
        for (int p = 0; p < 8; ++p) {
            const int e = p * 256 + tid, m = e >> 5, q = e & 31;
            *reinterpret_cast<float4*>(&dst[m * 128 + (q ^ (m & 31)) * 4]) = ld[p];
        }
    };
    auto comp = [&](int kc, int buf) {
        const bool isX = (kc < 8);
        const int kb = (kc & 7) * 128;
        const float* wb = (isX ? w_ih : w_hh) + (size_t)row0 * 1024 + kb;
        const float* sb = smem + buf * 8192 + lane * 128;
        const int msw = lane & 31;
#pragma unroll 4
        for (int q = 0; q < 32; ++q) {
            const float4 a = *reinterpret_cast<const float4*>(&sb[(q ^ msw) * 4]);
#pragma unroll
            for (int ci = 0; ci < 8; ++ci) {
                const float4 wv =
                    *reinterpret_cast<const float4*>(wb + (size_t)ci * 1024 + q * 4);
                acc[ci] = fmaf(a.x, wv.x, fmaf(a.y, wv.y,
                          fmaf(a.z, wv.z, fmaf(a.w, wv.w, acc[ci]))));
            }
        }
    };
    issue(0); wstage(0); __syncthreads();
    for (int kc = 0; kc < 16; ++kc) {
        if (kc < 15) issue(kc + 1);
        comp(kc, kc & 1);
        __syncthreads();
        if (kc < 15) { wstage((kc + 1) & 1); __syncthreads(); }
    }
#pragma unroll
    for (int ci = 0; ci < 8; ++ci) smem[g * 512 + ci * 64 + lane] = acc[ci];
    __syncthreads();
    float* cslot = out + (dir ? OUT_CTB : OUT_CTF);
    float* hslot = out + (dir ? OUT_HTB : OUT_HTF);
    const float* cinit = dir ? c0b : c0f;
#pragma unroll
    for (int s2 = 0; s2 < 2; ++s2) {
        const int idx = s2 * 256 + tid;
        const int u = idx & 7, m = idx >> 3, uu = u0 + u;
        const float ig = smem[0 * 512 + u * 64 + m];
        const float fg = smem[1 * 512 + u * 64 + m];
        const float gg = smem[2 * 512 + u * 64 + m];
        const float og = smem[3 * 512 + u * 64 + m];
        const float cp = (step == 0) ? cinit[m * H_DIM + uu]
                                     : cslot[m * H_DIM + uu];
        const float cn = sigmoidf_(fg) * cp + sigmoidf_(ig) * tanhf(gg);
        const float h = sigmoidf_(og) * tanhf(cn);
        cslot[m * H_DIM + uu] = cn;
        out[(size_t)t * B_DIM * 2 * H_DIM + m * 2 * H_DIM + dir * H_DIM + uu] = h;
        if (step == T_DIM - 1) hslot[m * H_DIM + uu] = h;
    }
}

extern "C" void kernel_launch(void* const* d_in, const int* in_sizes, int n_in,
                              void* d_out, int out_size, void* d_ws, size_t ws_size,
                              hipStream_t stream)
{
    const float* x    = (const float*)d_in[0];
    const float* h0f  = (const float*)d_in[1];
    const float* c0f  = (const float*)d_in[2];
    const float* h0b  = (const float*)d_in[3];
    const float* c0b  = (const float*)d_in[4];
    const float* wihf = (const float*)d_in[5];
    const float* whhf = (const float*)d_in[6];
    const float* bihf = (const float*)d_in[7];
    const float* bhhf = (const float*)d_in[8];
    const float* wihb = (const float*)d_in[9];
    const float* whhb = (const float*)d_in[10];
    const float* bihb = (const float*)d_in[11];
    const float* bhhb = (const float*)d_in[12];
    float* out = (float*)d_out;

    // ws: [0,256) barrier counters, [256, 256+4MB) gx ring (2 slots x 2 MB)
    const size_t NEED = 256 + 2ull * 2 * 64 * 64 * 64 * 4;
    if (ws_size >= NEED) {
        hipMemsetAsync(d_ws, 0, 256, stream);
        float* gx = (float*)((char*)d_ws + 256);
        lstm_pc<<<dim3(256), dim3(512), 0, stream>>>(
            x, h0f, c0f, h0b, c0b,
            wihf, whhf, bihf, bhhf,
            wihb, whhb, bihb, bhhb,
            out, gx, (int*)d_ws);
    } else {
        for (int s = 0; s < T_DIM; ++s) {
            lstm_step_fused<<<dim3(256), dim3(256), 0, stream>>>(
                x, h0f, c0f, h0b, c0b,
                wihf, whhf, bihf, bhhf,
                wihb, whhb, bihb, bhhb,
                out, s);
        }
    }
}